// Round 1
// baseline (611.000 us; speedup 1.0000x reference)
//
#include <hip/hip_runtime.h>
#include <hip/hip_bf16.h>

#define M_BATCH 16384
#define N_DIM   2048
#define K_DIM   2048

typedef __attribute__((ext_vector_type(8))) short bf16x8;   // 8 bf16 = 4 VGPRs
typedef __attribute__((ext_vector_type(4))) float f32x4;

// ---------- fp32 -> bf16 (RNE) conversion, 8 elements/thread ----------
__device__ __forceinline__ unsigned short f2bf_rne(float f) {
    union { float f; unsigned int u; } v; v.f = f;
    unsigned int r = v.u + 0x7fffu + ((v.u >> 16) & 1u);
    return (unsigned short)(r >> 16);
}

__global__ __launch_bounds__(256) void cvt_f32_bf16_x8(
        const float* __restrict__ src, unsigned short* __restrict__ dst, int n8) {
    int i = blockIdx.x * blockDim.x + threadIdx.x;
    if (i >= n8) return;
    const float4* s4 = (const float4*)src;
    float4 a = s4[2 * i];
    float4 b = s4[2 * i + 1];
    union { unsigned short h[8]; uint4 v; } r;
    r.h[0] = f2bf_rne(a.x); r.h[1] = f2bf_rne(a.y);
    r.h[2] = f2bf_rne(a.z); r.h[3] = f2bf_rne(a.w);
    r.h[4] = f2bf_rne(b.x); r.h[5] = f2bf_rne(b.y);
    r.h[6] = f2bf_rne(b.z); r.h[7] = f2bf_rne(b.w);
    ((uint4*)dst)[i] = r.v;
}

// ---------- async global->LDS, 16B per lane ----------
__device__ __forceinline__ void gld_lds16(const void* g, void* l) {
    __builtin_amdgcn_global_load_lds(
        (const __attribute__((address_space(1))) void*)g,
        (__attribute__((address_space(3))) void*)l, 16, 0, 0);
}

// ---------- fused GEMM: out = sigmoid(decay)*h + Xb @ Wb^T + bias, written twice ----------
// Xb: [M,K] bf16 row-major; Wb: [N,K] bf16 row-major (B^T-input GEMM)
// Block tile 128x128, BK=32, 256 threads = 4 waves in 2x2, each wave 64x64 (4x4 MFMA tiles)
__global__ __launch_bounds__(256, 2) void lrnn_gemm_fused(
        const unsigned short* __restrict__ Xb,
        const unsigned short* __restrict__ Wb,
        const float* __restrict__ H,
        const float* __restrict__ bias,
        const float* __restrict__ decay,
        float* __restrict__ out) {
    // No padding: global_load_lds writes wave-uniform base + lane*16 contiguously.
    __shared__ __align__(16) unsigned short As[128 * 32];
    __shared__ __align__(16) unsigned short Bs[128 * 32];

    const int tid  = threadIdx.x;
    const int wave = tid >> 6;
    const int lane = tid & 63;
    const int quad = lane >> 4;
    const int l16  = lane & 15;

    const int row0 = blockIdx.y * 128;
    const int col0 = blockIdx.x * 128;
    const int wm = (wave >> 1) * 64;   // wave row offset within tile
    const int wn = (wave & 1) * 64;    // wave col offset within tile

    // Staging: tile = 128 rows x 32 bf16 = 512 chunks of 16B (4 chunks/row).
    // Wave w stages chunks [w*64+lane] (seg0) and [256+w*64+lane] (seg1).
    const int t0  = wave * 64 + lane;
    const int r0s = t0 >> 2, kc0 = (t0 & 3) * 8;
    const int t1  = 256 + t0;
    const int r1s = t1 >> 2, kc1 = (t1 & 3) * 8;

    const unsigned short* gA0 = Xb + (size_t)(row0 + r0s) * K_DIM + kc0;
    const unsigned short* gA1 = Xb + (size_t)(row0 + r1s) * K_DIM + kc1;
    const unsigned short* gB0 = Wb + (size_t)(col0 + r0s) * K_DIM + kc0;
    const unsigned short* gB1 = Wb + (size_t)(col0 + r1s) * K_DIM + kc1;

    unsigned short* lA0 = As + (wave * 64) * 8;          // wave-uniform LDS bases
    unsigned short* lA1 = As + (256 + wave * 64) * 8;
    unsigned short* lB0 = Bs + (wave * 64) * 8;
    unsigned short* lB1 = Bs + (256 + wave * 64) * 8;

    f32x4 acc[4][4] = {};

    for (int k0 = 0; k0 < K_DIM; k0 += 32) {
        gld_lds16(gA0 + k0, lA0);
        gld_lds16(gA1 + k0, lA1);
        gld_lds16(gB0 + k0, lB0);
        gld_lds16(gB1 + k0, lB1);
        __syncthreads();

        bf16x8 af[4], bfr[4];
#pragma unroll
        for (int i = 0; i < 4; ++i) {
            // A-operand: m = lane&15, k = quad*8 + j
            af[i]  = *(const bf16x8*)(As + (wm + i * 16 + l16) * 32 + quad * 8);
            // B-operand: n = lane&15, k = quad*8 + j
            bfr[i] = *(const bf16x8*)(Bs + (wn + i * 16 + l16) * 32 + quad * 8);
        }
#pragma unroll
        for (int i = 0; i < 4; ++i)
#pragma unroll
            for (int j = 0; j < 4; ++j)
                acc[i][j] = __builtin_amdgcn_mfma_f32_16x16x32_bf16(
                    af[i], bfr[j], acc[i][j], 0, 0, 0);
        __syncthreads();
    }

    // Epilogue. C/D layout (16x16): col = lane&15, row = quad*4 + reg
    const size_t MN = (size_t)M_BATCH * N_DIM;
#pragma unroll
    for (int j = 0; j < 4; ++j) {
        const int col = col0 + wn + j * 16 + l16;
        const float al = 1.0f / (1.0f + __expf(-decay[col]));
        const float bb = bias[col];
#pragma unroll
        for (int i = 0; i < 4; ++i) {
            const int row = row0 + wm + i * 16 + quad * 4;
#pragma unroll
            for (int r = 0; r < 4; ++r) {
                size_t idx = (size_t)(row + r) * N_DIM + col;
                float v = al * H[idx] + acc[i][j][r] + bb;
                out[idx] = v;
                out[MN + idx] = v;
            }
        }
    }
}

extern "C" void kernel_launch(void* const* d_in, const int* in_sizes, int n_in,
                              void* d_out, int out_size, void* d_ws, size_t ws_size,
                              hipStream_t stream) {
    const float* x     = (const float*)d_in[0];
    const float* h     = (const float*)d_in[1];
    const float* W     = (const float*)d_in[2];
    const float* b     = (const float*)d_in[3];
    const float* decay = (const float*)d_in[4];
    float* out = (float*)d_out;

    unsigned short* xb = (unsigned short*)d_ws;                 // [M,K] bf16: 64 MiB
    unsigned short* wb = xb + (size_t)M_BATCH * K_DIM;          // [N,K] bf16:  8 MiB

    const int n8x = M_BATCH * K_DIM / 8;
    cvt_f32_bf16_x8<<<n8x / 256, 256, 0, stream>>>(x, xb, n8x);
    const int n8w = N_DIM * K_DIM / 8;
    cvt_f32_bf16_x8<<<n8w / 256, 256, 0, stream>>>(W, wb, n8w);

    dim3 grid(N_DIM / 128, M_BATCH / 128);   // (16, 128)
    lrnn_gemm_fused<<<grid, 256, 0, stream>>>(xb, wb, h, b, decay, out);
}